// Round 2
// baseline (423.744 us; speedup 1.0000x reference)
//
#include <hip/hip_runtime.h>

typedef unsigned short u16;
typedef unsigned int   u32;

#define S_  2048
#define D_  64
#define NR_ 4
#define NB_ 32

__device__ __forceinline__ float bf2f(u16 u){ return __uint_as_float(((u32)u)<<16); }
__device__ __forceinline__ u16 f2bf(float f){
  u32 u = __float_as_uint(f);
  u32 r = (u + 0x7fffu + ((u>>16)&1u)) >> 16;
  return (u16)r;
}
__device__ __forceinline__ void unpack2(u32 w, float &a, float &b){
  a = __uint_as_float(w<<16);
  b = __uint_as_float(w & 0xffff0000u);
}

// ---------------------------------------------------------------------------
// K1: proj = q . R  (f32, sequential over d), argmax over [proj, -proj] -> h
// grid: 256 blocks (b = blk>>3, 256 positions per block), 256 threads
// ---------------------------------------------------------------------------
__global__ __launch_bounds__(256) void k_hash(const float* __restrict__ q,
                                              const float* __restrict__ R,
                                              int* __restrict__ hout){
  __shared__ float Rl[64][64];              // [d][r*16+k]
  int b   = blockIdx.x >> 3;
  int pos = (blockIdx.x & 7) * 256 + threadIdx.x;
  const float* Rb = R + (size_t)b * 4096;
  for (int idx = threadIdx.x; idx < 4096; idx += 256)
    Rl[idx >> 6][idx & 63] = Rb[idx];
  __syncthreads();

  const float4* q4 = (const float4*)(q + ((size_t)b * S_ + pos) * D_);
  float acc[64];
  #pragma unroll
  for (int i = 0; i < 64; i++) acc[i] = 0.f;

  #pragma unroll
  for (int c = 0; c < 16; c++){
    float4 w = q4[c];
    float qd[4] = {w.x, w.y, w.z, w.w};
    #pragma unroll
    for (int dd = 0; dd < 4; dd++){
      int d = c * 4 + dd;
      const float4* Rr = (const float4*)(&Rl[d][0]);
      #pragma unroll
      for (int k4 = 0; k4 < 16; k4++){
        float4 rv = Rr[k4];
        acc[k4*4+0] += qd[dd] * rv.x;
        acc[k4*4+1] += qd[dd] * rv.y;
        acc[k4*4+2] += qd[dd] * rv.z;
        acc[k4*4+3] += qd[dd] * rv.w;
      }
    }
  }
  #pragma unroll
  for (int r = 0; r < 4; r++){
    float bv = acc[r*16]; int bi = 0;
    #pragma unroll
    for (int m = 1; m < 32; m++){
      float v = (m < 16) ? acc[r*16 + m] : -acc[r*16 + m - 16];
      if (v > bv){ bv = v; bi = m; }   // strict >: first max wins (matches argmax)
    }
    hout[((size_t)b * NR_ + r) * S_ + pos] = bi;
  }
}

// ---------------------------------------------------------------------------
// K2: stable counting sort on 32 bins per (b,r). 128 blocks, 256 threads.
// thread t owns positions [8t, 8t+8). Emits sort_idx and chunk(p)=slot>>6.
// ---------------------------------------------------------------------------
__global__ __launch_bounds__(256) void k_sort(const int* __restrict__ h,
                                              int* __restrict__ sidx,
                                              int* __restrict__ chk){
  __shared__ int cnt[32][257];
  __shared__ int base[32];
  int br = blockIdx.x;
  const int* hb = h + (size_t)br * S_;
  int t = threadIdx.x;

  #pragma unroll
  for (int hh = 0; hh < 32; hh++) cnt[hh][t] = 0;
  __syncthreads();

  int hv[8];
  const int4* hb4 = (const int4*)hb;
  int4 a0 = hb4[t*2], a1 = hb4[t*2+1];
  hv[0]=a0.x; hv[1]=a0.y; hv[2]=a0.z; hv[3]=a0.w;
  hv[4]=a1.x; hv[5]=a1.y; hv[6]=a1.z; hv[7]=a1.w;
  #pragma unroll
  for (int k = 0; k < 8; k++) cnt[hv[k]][t]++;   // column t is thread-private
  __syncthreads();

  // per-h exclusive scan over threads: wave w handles h = 8w..8w+7
  int wave = t >> 6, lane = t & 63;
  for (int hh = wave*8; hh < wave*8 + 8; hh++){
    int vals[4]; int s0 = 0;
    #pragma unroll
    for (int k = 0; k < 4; k++){ vals[k] = cnt[hh][lane*4+k]; s0 += vals[k]; }
    int incl = s0;
    #pragma unroll
    for (int off = 1; off < 64; off <<= 1){
      int o = __shfl_up(incl, off, 64);
      if (lane >= off) incl += o;
    }
    int run = incl - s0;
    #pragma unroll
    for (int k = 0; k < 4; k++){ int tmp = vals[k]; cnt[hh][lane*4+k] = run; run += tmp; }
    if (lane == 63) base[hh] = incl;   // total count of bin hh
  }
  __syncthreads();
  if (t == 0){
    int run = 0;
    #pragma unroll
    for (int hh = 0; hh < 32; hh++){ int tot = base[hh]; base[hh] = run; run += tot; }
  }
  __syncthreads();

  int p0 = t * 8;
  #pragma unroll
  for (int k = 0; k < 8; k++){
    int hh = hv[k];
    int c = cnt[hh][t];
    int slot = base[hh] + c;
    cnt[hh][t] = c + 1;                        // stability within thread
    sidx[(size_t)br * S_ + slot]    = p0 + k;
    chk [(size_t)br * S_ + p0 + k]  = slot >> 6;
  }
}

// ---------------------------------------------------------------------------
// K3: per (b, r, bucket n): Q(64xD) vs K(128xD) attention, scatter att/lse
// grid: 4096 blocks (blk = (b*4+r)*32+n), 256 threads
// ---------------------------------------------------------------------------
__global__ __launch_bounds__(256) void k_attn(const float* __restrict__ q,
                                              const float* __restrict__ v,
                                              const int* __restrict__ sidx,
                                              const int* __restrict__ chk,
                                              float* __restrict__ lse_ws,
                                              u16*  __restrict__ att_ws){
  __shared__ u16   A[128][88];     // gathered rows as bf16 (stride 88 shorts)
  __shared__ float SM[64][132];    // logits then probabilities
  __shared__ int   pkey[128];
  __shared__ float rcnt[128];
  __shared__ float sc[128];        // rsqrt(|k|^2) / sqrt(D)

  int blk = blockIdx.x;
  int b = blk >> 7;
  int r = (blk >> 5) & 3;
  int n = blk & 31;
  int npv = (n + 31) & 31;
  int t = threadIdx.x;
  const int* sb = sidx + ((size_t)b * NR_ + r) * S_;

  if (t < 128){
    int p = (t < 64) ? sb[npv*64 + t] : sb[n*64 + (t - 64)];
    pkey[t] = p;
    int c = 0;
    #pragma unroll
    for (int rr = 0; rr < 4; rr++){
      int ch = chk[((size_t)b * NR_ + rr) * S_ + p];
      c += (ch == n) || (ch == npv);
    }
    if (c < 1) c = 1;
    rcnt[t] = 1.0f / (float)c;
  }
  __syncthreads();

  { // gather Q rows (f32 -> bf16) for all 128 keys (rows 64.. are the queries)
    int row = t >> 1, half = t & 1;
    const float4* src = (const float4*)(q + ((size_t)b * S_ + pkey[row]) * D_) + half*8;
    u32 buf[16];
    #pragma unroll
    for (int k = 0; k < 8; k++){
      float4 w = src[k];
      buf[k*2+0] = (u32)f2bf(w.x) | ((u32)f2bf(w.y) << 16);
      buf[k*2+1] = (u32)f2bf(w.z) | ((u32)f2bf(w.w) << 16);
    }
    uint4* dst = (uint4*)(&A[row][half*32]);
    #pragma unroll
    for (int k = 0; k < 4; k++)
      dst[k] = make_uint4(buf[k*4+0], buf[k*4+1], buf[k*4+2], buf[k*4+3]);
  }
  __syncthreads();

  if (t < 128){ // key norm factors
    float s = 0.f;
    const uint2* rowp = (const uint2*)(&A[t][0]);
    #pragma unroll
    for (int c = 0; c < 16; c++){
      uint2 w = rowp[c];
      float f0,f1,f2,f3;
      unpack2(w.x,f0,f1); unpack2(w.y,f2,f3);
      s += f0*f0 + f1*f1 + f2*f2 + f3*f3;
    }
    sc[t] = rsqrtf(fmaxf(s, 1e-12f)) * 0.125f;   // 1/sqrt(64)
  }
  __syncthreads();

  { // QK^T: thread tile = rows i0..i0+3 (contig), cols j = tj + 16*jj (strided)
    int ti = t >> 4, tj = t & 15;
    int i0 = ti * 4;
    float acc[4][8];
    #pragma unroll
    for (int ii = 0; ii < 4; ii++)
      #pragma unroll
      for (int jj = 0; jj < 8; jj++) acc[ii][jj] = 0.f;

    #pragma unroll 2
    for (int e = 0; e < 64; e += 8){
      float qf[4][8];
      #pragma unroll
      for (int ii = 0; ii < 4; ii++){
        uint4 w = *(const uint4*)(&A[64 + i0 + ii][e]);
        unpack2(w.x, qf[ii][0], qf[ii][1]); unpack2(w.y, qf[ii][2], qf[ii][3]);
        unpack2(w.z, qf[ii][4], qf[ii][5]); unpack2(w.w, qf[ii][6], qf[ii][7]);
      }
      #pragma unroll
      for (int jj = 0; jj < 8; jj++){
        uint4 w = *(const uint4*)(&A[tj + 16*jj][e]);
        float kf[8];
        unpack2(w.x, kf[0], kf[1]); unpack2(w.y, kf[2], kf[3]);
        unpack2(w.z, kf[4], kf[5]); unpack2(w.w, kf[6], kf[7]);
        #pragma unroll
        for (int ii = 0; ii < 4; ii++)
          #pragma unroll
          for (int m = 0; m < 8; m++) acc[ii][jj] += qf[ii][m] * kf[m];
      }
    }
    #pragma unroll
    for (int jj = 0; jj < 8; jj++){
      int j = tj + 16*jj;
      float scj = sc[j];
      int pj = pkey[j];
      #pragma unroll
      for (int ii = 0; ii < 4; ii++){
        int i = i0 + ii;
        int pi = pkey[64 + i];
        float l = acc[ii][jj] * scj;
        if (pi < pj)       l = -1000000000.0f;
        else if (pi == pj) l = -100000.0f;
        SM[i][j] = l;
      }
    }
  }
  __syncthreads();

  { // gather V rows f32->bf16 (overwrites A; qk reads done at barrier)
    int row = t >> 1, half = t & 1;
    const float4* src = (const float4*)(v + ((size_t)b * S_ + pkey[row]) * D_) + half*8;
    u32 buf[16];
    #pragma unroll
    for (int k = 0; k < 8; k++){
      float4 w = src[k];
      buf[k*2+0] = (u32)f2bf(w.x) | ((u32)f2bf(w.y) << 16);
      buf[k*2+1] = (u32)f2bf(w.z) | ((u32)f2bf(w.w) << 16);
    }
    uint4* dst = (uint4*)(&A[row][half*32]);
    #pragma unroll
    for (int k = 0; k < 4; k++)
      dst[k] = make_uint4(buf[k*4+0], buf[k*4+1], buf[k*4+2], buf[k*4+3]);
  }
  if (t < 64){ // row softmax + dup-count scaling + lse scatter
    float mx = -3.0e38f;
    #pragma unroll
    for (int j = 0; j < 128; j += 4){
      float4 w = *(const float4*)(&SM[t][j]);
      mx = fmaxf(mx, fmaxf(fmaxf(w.x, w.y), fmaxf(w.z, w.w)));
    }
    float sum = 0.f;
    #pragma unroll 4
    for (int j = 0; j < 128; j++) sum += __expf(SM[t][j] - mx);
    float lse = mx + __logf(sum);
    float inv = 1.0f / sum;
    #pragma unroll 4
    for (int j = 0; j < 128; j++) SM[t][j] = __expf(SM[t][j] - mx) * inv * rcnt[j];
    lse_ws[((size_t)b * S_ + pkey[64 + t]) * NR_ + r] = lse;
  }
  __syncthreads();

  { // att = SM(64x128) . V(128x64); thread tile 4 rows x 4 cols
    int ti = t >> 4, td = t & 15;
    int i0 = ti * 4, d0 = td * 4;
    float acc[4][4];
    #pragma unroll
    for (int ii = 0; ii < 4; ii++)
      #pragma unroll
      for (int dd = 0; dd < 4; dd++) acc[ii][dd] = 0.f;

    #pragma unroll 4
    for (int j = 0; j < 128; j++){
      uint2 w = *(const uint2*)(&A[j][d0]);
      float v0,v1,v2,v3;
      unpack2(w.x, v0, v1); unpack2(w.y, v2, v3);
      #pragma unroll
      for (int ii = 0; ii < 4; ii++){
        float s = SM[i0 + ii][j];
        acc[ii][0] += s * v0; acc[ii][1] += s * v1;
        acc[ii][2] += s * v2; acc[ii][3] += s * v3;
      }
    }
    #pragma unroll
    for (int ii = 0; ii < 4; ii++){
      int i = i0 + ii;
      int p = pkey[64 + i];
      u32 w0 = (u32)f2bf(acc[ii][0]) | ((u32)f2bf(acc[ii][1]) << 16);
      u32 w1 = (u32)f2bf(acc[ii][2]) | ((u32)f2bf(acc[ii][3]) << 16);
      uint2* dst = (uint2*)(att_ws + (((size_t)b * S_ + p) * NR_ + r) * D_ + d0);
      *dst = make_uint2(w0, w1);
    }
  }
}

// ---------------------------------------------------------------------------
// K4: per position softmax over round LSEs, weighted sum of round outputs
// ---------------------------------------------------------------------------
__global__ __launch_bounds__(256) void k_comb(const float* __restrict__ lse_ws,
                                              const u16* __restrict__ att_ws,
                                              float* __restrict__ out){
  size_t idx = (size_t)blockIdx.x * 256 + threadIdx.x;   // over B*S*D
  size_t pd = idx >> 6;
  int d = (int)(idx & 63);
  float4 lv = *(const float4*)(lse_ws + pd * 4);
  float m = fmaxf(fmaxf(lv.x, lv.y), fmaxf(lv.z, lv.w));
  float e0 = __expf(lv.x - m), e1 = __expf(lv.y - m);
  float e2 = __expf(lv.z - m), e3 = __expf(lv.w - m);
  float inv = 1.0f / (e0 + e1 + e2 + e3);
  const u16* a = att_ws + pd * 256 + d;
  float o = (bf2f(a[0])   * e0 + bf2f(a[64])  * e1 +
             bf2f(a[128]) * e2 + bf2f(a[192]) * e3) * inv;
  out[idx] = o;
}

// ---------------------------------------------------------------------------
extern "C" void kernel_launch(void* const* d_in, const int* in_sizes, int n_in,
                              void* d_out, int out_size, void* d_ws, size_t ws_size,
                              hipStream_t stream){
  const float* q = (const float*)d_in[0];   // (32,2048,64) f32
  const float* v = (const float*)d_in[1];   // (32,2048,64) f32
  const float* R = (const float*)d_in[2];   // (32,64,4,16) f32

  char* w = (char*)d_ws;
  int*   h    = (int*)  (w + 0);                 // (32,4,2048) i32   1 MB
  int*   sidx = (int*)  (w + (1u << 20));        // (32,4,2048) i32   1 MB
  int*   chkA = (int*)  (w + (2u << 20));        // (32,4,2048) i32   1 MB
  float* lse  = (float*)(w + (3u << 20));        // (32,2048,4) f32   1 MB
  u16*   att  = (u16*)  (w + (4u << 20));        // (32,2048,4,64) bf16  32 MB
  float* out  = (float*)d_out;

  k_hash<<<256,  256, 0, stream>>>(q, R, h);
  k_sort<<<128,  256, 0, stream>>>(h, sidx, chkA);
  k_attn<<<4096, 256, 0, stream>>>(q, v, sidx, chkA, lse, att);
  k_comb<<<16384,256, 0, stream>>>(lse, att, out);
}

// Round 3
// 159.651 us; speedup vs baseline: 2.6542x; 2.6542x over previous
//
#include <hip/hip_runtime.h>

typedef unsigned short u16;
typedef unsigned int   u32;
typedef short bf16x8 __attribute__((ext_vector_type(8)));
typedef float f32x16 __attribute__((ext_vector_type(16)));

#define S_  2048
#define D_  64
#define NR_ 4
#define NB_ 32

#define AS 72    // A tile row stride (shorts), 144 B (16B-aligned)
#define VS 136   // Vt row stride (shorts), 272 B
#define PS 136   // SM row stride (shorts), 272 B

__device__ __forceinline__ float bf2f(u16 u){ return __uint_as_float(((u32)u)<<16); }
__device__ __forceinline__ u16 f2bf(float f){
  u32 u = __float_as_uint(f);
  u32 r = (u + 0x7fffu + ((u>>16)&1u)) >> 16;
  return (u16)r;
}
__device__ __forceinline__ void unpack2(u32 w, float &a, float &b){
  a = __uint_as_float(w<<16);
  b = __uint_as_float(w & 0xffff0000u);
}
__device__ __forceinline__ bf16x8 ld8(const u16* p){
  union { uint4 u; bf16x8 v; } x;
  x.u = *(const uint4*)p;
  return x.v;
}

// ---------------------------------------------------------------------------
// K1: proj = q . R  (f32, sequential over d), argmax over [proj, -proj] -> h
// ---------------------------------------------------------------------------
__global__ __launch_bounds__(256) void k_hash(const float* __restrict__ q,
                                              const float* __restrict__ R,
                                              int* __restrict__ hout){
  __shared__ float Rl[64][64];              // [d][r*16+k]
  int b   = blockIdx.x >> 3;
  int pos = (blockIdx.x & 7) * 256 + threadIdx.x;
  const float* Rb = R + (size_t)b * 4096;
  for (int idx = threadIdx.x; idx < 4096; idx += 256)
    Rl[idx >> 6][idx & 63] = Rb[idx];
  __syncthreads();

  const float4* q4 = (const float4*)(q + ((size_t)b * S_ + pos) * D_);
  float acc[64];
  #pragma unroll
  for (int i = 0; i < 64; i++) acc[i] = 0.f;

  #pragma unroll
  for (int c = 0; c < 16; c++){
    float4 w = q4[c];
    float qd[4] = {w.x, w.y, w.z, w.w};
    #pragma unroll
    for (int dd = 0; dd < 4; dd++){
      int d = c * 4 + dd;
      const float4* Rr = (const float4*)(&Rl[d][0]);
      #pragma unroll
      for (int k4 = 0; k4 < 16; k4++){
        float4 rv = Rr[k4];
        acc[k4*4+0] += qd[dd] * rv.x;
        acc[k4*4+1] += qd[dd] * rv.y;
        acc[k4*4+2] += qd[dd] * rv.z;
        acc[k4*4+3] += qd[dd] * rv.w;
      }
    }
  }
  #pragma unroll
  for (int r = 0; r < 4; r++){
    float bv = acc[r*16]; int bi = 0;
    #pragma unroll
    for (int m = 1; m < 32; m++){
      float v = (m < 16) ? acc[r*16 + m] : -acc[r*16 + m - 16];
      if (v > bv){ bv = v; bi = m; }
    }
    hout[((size_t)b * NR_ + r) * S_ + pos] = bi;
  }
}

// ---------------------------------------------------------------------------
// K2: stable counting sort on 32 bins per (b,r).
// ---------------------------------------------------------------------------
__global__ __launch_bounds__(256) void k_sort(const int* __restrict__ h,
                                              int* __restrict__ sidx,
                                              int* __restrict__ chk){
  __shared__ int cnt[32][257];
  __shared__ int base[32];
  int br = blockIdx.x;
  const int* hb = h + (size_t)br * S_;
  int t = threadIdx.x;

  #pragma unroll
  for (int hh = 0; hh < 32; hh++) cnt[hh][t] = 0;
  __syncthreads();

  int hv[8];
  const int4* hb4 = (const int4*)hb;
  int4 a0 = hb4[t*2], a1 = hb4[t*2+1];
  hv[0]=a0.x; hv[1]=a0.y; hv[2]=a0.z; hv[3]=a0.w;
  hv[4]=a1.x; hv[5]=a1.y; hv[6]=a1.z; hv[7]=a1.w;
  #pragma unroll
  for (int k = 0; k < 8; k++) cnt[hv[k]][t]++;
  __syncthreads();

  int wave = t >> 6, lane = t & 63;
  for (int hh = wave*8; hh < wave*8 + 8; hh++){
    int vals[4]; int s0 = 0;
    #pragma unroll
    for (int k = 0; k < 4; k++){ vals[k] = cnt[hh][lane*4+k]; s0 += vals[k]; }
    int incl = s0;
    #pragma unroll
    for (int off = 1; off < 64; off <<= 1){
      int o = __shfl_up(incl, off, 64);
      if (lane >= off) incl += o;
    }
    int run = incl - s0;
    #pragma unroll
    for (int k = 0; k < 4; k++){ int tmp = vals[k]; cnt[hh][lane*4+k] = run; run += tmp; }
    if (lane == 63) base[hh] = incl;
  }
  __syncthreads();
  if (t == 0){
    int run = 0;
    #pragma unroll
    for (int hh = 0; hh < 32; hh++){ int tot = base[hh]; base[hh] = run; run += tot; }
  }
  __syncthreads();

  int p0 = t * 8;
  #pragma unroll
  for (int k = 0; k < 8; k++){
    int hh = hv[k];
    int c = cnt[hh][t];
    int slot = base[hh] + c;
    cnt[hh][t] = c + 1;
    sidx[(size_t)br * S_ + slot]    = p0 + k;
    chk [(size_t)br * S_ + p0 + k]  = slot >> 6;
  }
}

// ---------------------------------------------------------------------------
// K3: per (b, r, bucket n): MFMA attention. 4 waves/block.
// ---------------------------------------------------------------------------
__global__ __launch_bounds__(256, 4) void k_attn(const float* __restrict__ q,
                                                 const float* __restrict__ v,
                                                 const int* __restrict__ sidx,
                                                 const int* __restrict__ chk,
                                                 float* __restrict__ lse_ws,
                                                 u16*  __restrict__ att_ws){
  __shared__ u16 A[128*AS];      // Q/K tile row-major; later Vt[64][VS] (d-major)
  __shared__ u16 SM[64*PS];      // logits -> probs (bf16)
  __shared__ int   pkey[128];
  __shared__ float rcnt[128];
  __shared__ float sc[128];

  int blk = blockIdx.x;
  int b = blk >> 7, r = (blk >> 5) & 3, n = blk & 31;
  int npv = (n + 31) & 31;
  int t = threadIdx.x;
  int lane = t & 63, w = t >> 6;
  const int* sb = sidx + ((size_t)b * NR_ + r) * S_;

  if (t < 128){
    int p = (t < 64) ? sb[npv*64 + t] : sb[n*64 + (t - 64)];
    pkey[t] = p;
    int c = 0;
    #pragma unroll
    for (int rr = 0; rr < 4; rr++){
      int ch = chk[((size_t)b * NR_ + rr) * S_ + p];
      c += (ch == n) || (ch == npv);
    }
    if (c < 1) c = 1;
    rcnt[t] = 1.0f / (float)c;
  }
  __syncthreads();

  // ---- phase 1: issue Q/K row gathers + V column-pair gathers --------------
  int row = t >> 1, half = t & 1;        // Q/K: 2 threads per key row
  float4 qv[8];
  {
    const float4* src = (const float4*)(q + ((size_t)b*S_ + pkey[row])*D_) + half*8;
    #pragma unroll
    for (int k = 0; k < 8; k++) qv[k] = src[k];
  }
  int jp = t & 63, dgrp = t >> 6;        // V: key pair (2jp,2jp+1), d-range dgrp*16..+15
  float4 va[4], vb[4];
  {
    const float4* s0 = (const float4*)(v + ((size_t)b*S_ + pkey[2*jp  ])*D_) + dgrp*4;
    const float4* s1 = (const float4*)(v + ((size_t)b*S_ + pkey[2*jp+1])*D_) + dgrp*4;
    #pragma unroll
    for (int k = 0; k < 4; k++){ va[k] = s0[k]; vb[k] = s1[k]; }
  }
  { // convert+write Q/K tile, key sumsq -> sc
    float ss = 0.f;
    u32 buf[16];
    #pragma unroll
    for (int k = 0; k < 8; k++){
      float4 f = qv[k];
      u16 b0 = f2bf(f.x), b1 = f2bf(f.y), b2 = f2bf(f.z), b3 = f2bf(f.w);
      float g0 = bf2f(b0), g1 = bf2f(b1), g2 = bf2f(b2), g3 = bf2f(b3);
      ss += g0*g0 + g1*g1 + g2*g2 + g3*g3;
      buf[k*2]   = (u32)b0 | ((u32)b1 << 16);
      buf[k*2+1] = (u32)b2 | ((u32)b3 << 16);
    }
    uint4* dst = (uint4*)(&A[row*AS + half*32]);
    #pragma unroll
    for (int k = 0; k < 4; k++)
      dst[k] = make_uint4(buf[4*k], buf[4*k+1], buf[4*k+2], buf[4*k+3]);
    float ss2 = ss + __shfl_xor(ss, 1, 64);
    if (half == 0) sc[row] = rsqrtf(fmaxf(ss2, 1e-12f)) * 0.125f;
  }
  __syncthreads();

  // ---- phase 2: S = Q.K^T via MFMA ----------------------------------------
  int Mt = w & 1, Nt0 = (w >> 1) * 2;
  f32x16 acc0, acc1;
  #pragma unroll
  for (int i = 0; i < 16; i++){ acc0[i] = 0.f; acc1[i] = 0.f; }
  {
    int mrow  = (64 + Mt*32 + (lane & 31)) * AS;
    int krow0 = (Nt0*32 + (lane & 31)) * AS;
    int krow1 = krow0 + 32*AS;
    int coff  = (lane >> 5) * 8;
    #pragma unroll
    for (int ks = 0; ks < 4; ks++){
      int o = ks*16 + coff;
      bf16x8 af = ld8(&A[mrow  + o]);
      bf16x8 b0 = ld8(&A[krow0 + o]);
      bf16x8 b1 = ld8(&A[krow1 + o]);
      acc0 = __builtin_amdgcn_mfma_f32_32x32x16_bf16(af, b0, acc0, 0, 0, 0);
      acc1 = __builtin_amdgcn_mfma_f32_32x32x16_bf16(af, b1, acc1, 0, 0, 0);
    }
  }
  { // masks + scale, store bf16 logits to SM
    int h = lane >> 5;
    int pi[16];
    #pragma unroll
    for (int reg = 0; reg < 16; reg++){
      int il = (reg & 3) + 8*(reg >> 2) + 4*h;
      pi[reg] = pkey[64 + Mt*32 + il];
    }
    #pragma unroll
    for (int e = 0; e < 2; e++){
      int j = (Nt0 + e)*32 + (lane & 31);
      int pj = pkey[j];
      float scj = sc[j];
      #pragma unroll
      for (int reg = 0; reg < 16; reg++){
        int il = (reg & 3) + 8*(reg >> 2) + 4*h;
        float l = (e ? acc1[reg] : acc0[reg]) * scj;
        if (pi[reg] < pj)       l = -1000000000.0f;
        else if (pi[reg] == pj) l = -100000.0f;
        SM[(Mt*32 + il)*PS + j] = f2bf(l);
      }
    }
  }
  __syncthreads();

  // ---- phase 3: row softmax (4 threads per row), lse scatter --------------
  {
    int srow = t >> 2, seg = t & 3;
    uint4 u[4];
    const uint4* p4 = (const uint4*)(&SM[srow*PS + seg*32]);
    #pragma unroll
    for (int k = 0; k < 4; k++) u[k] = p4[k];
    float vals[32];
    #pragma unroll
    for (int k = 0; k < 4; k++){
      unpack2(u[k].x, vals[k*8+0], vals[k*8+1]);
      unpack2(u[k].y, vals[k*8+2], vals[k*8+3]);
      unpack2(u[k].z, vals[k*8+4], vals[k*8+5]);
      unpack2(u[k].w, vals[k*8+6], vals[k*8+7]);
    }
    float mx = -3.0e38f;
    #pragma unroll
    for (int k = 0; k < 32; k++) mx = fmaxf(mx, vals[k]);
    mx = fmaxf(mx, __shfl_xor(mx, 1, 64));
    mx = fmaxf(mx, __shfl_xor(mx, 2, 64));
    float s = 0.f;
    #pragma unroll
    for (int k = 0; k < 32; k++) s += __expf(vals[k] - mx);
    s += __shfl_xor(s, 1, 64);
    s += __shfl_xor(s, 2, 64);
    float inv = 1.0f / s;
    u32 ob[16];
    #pragma unroll
    for (int k = 0; k < 16; k++){
      u16 p0 = f2bf(__expf(vals[2*k]   - mx) * inv);
      u16 p1 = f2bf(__expf(vals[2*k+1] - mx) * inv);
      ob[k] = (u32)p0 | ((u32)p1 << 16);
    }
    uint4* d4 = (uint4*)(&SM[srow*PS + seg*32]);
    #pragma unroll
    for (int k = 0; k < 4; k++)
      d4[k] = make_uint4(ob[4*k], ob[4*k+1], ob[4*k+2], ob[4*k+3]);
    if (seg == 0)
      lse_ws[((size_t)b*S_ + pkey[64 + srow])*NR_ + r] = mx + __logf(s);
  }
  __syncthreads();

  // ---- phase 4: Vt = (rcnt-scaled V)^T, overwriting A ---------------------
  {
    float ra = rcnt[2*jp], rb = rcnt[2*jp+1];
    u32 vt[16];
    #pragma unroll
    for (int k = 0; k < 4; k++){
      float4 fa = va[k], fb = vb[k];
      vt[k*4+0] = (u32)f2bf(fa.x*ra) | ((u32)f2bf(fb.x*rb) << 16);
      vt[k*4+1] = (u32)f2bf(fa.y*ra) | ((u32)f2bf(fb.y*rb) << 16);
      vt[k*4+2] = (u32)f2bf(fa.z*ra) | ((u32)f2bf(fb.z*rb) << 16);
      vt[k*4+3] = (u32)f2bf(fa.w*ra) | ((u32)f2bf(fb.w*rb) << 16);
    }
    u32* vtp = (u32*)A;
    #pragma unroll
    for (int k = 0; k < 16; k++){
      int d = dgrp*16 + k;
      vtp[d*(VS/2) + jp] = vt[k];
    }
  }
  __syncthreads();

  // ---- phase 5: out = P.V via MFMA, scatter bf16 --------------------------
  {
    int Mt2 = w >> 1, Nt2 = w & 1;
    f32x16 acc;
    #pragma unroll
    for (int i = 0; i < 16; i++) acc[i] = 0.f;
    int prow = (Mt2*32 + (lane & 31)) * PS;
    int vrow = (Nt2*32 + (lane & 31)) * VS;
    int coff = (lane >> 5) * 8;
    #pragma unroll
    for (int ks = 0; ks < 8; ks++){
      int o = ks*16 + coff;
      bf16x8 af = ld8(&SM[prow + o]);
      bf16x8 bf = ld8(&A[vrow + o]);
      acc = __builtin_amdgcn_mfma_f32_32x32x16_bf16(af, bf, acc, 0, 0, 0);
    }
    int h = lane >> 5;
    int dcol = Nt2*32 + (lane & 31);
    #pragma unroll
    for (int reg = 0; reg < 16; reg++){
      int il = (reg & 3) + 8*(reg >> 2) + 4*h;
      int p = pkey[64 + Mt2*32 + il];
      att_ws[(((size_t)b*S_ + p)*NR_ + r)*D_ + dcol] = f2bf(acc[reg]);
    }
  }
}

// ---------------------------------------------------------------------------
// K4: per position softmax over round LSEs, weighted sum of round outputs
// ---------------------------------------------------------------------------
__global__ __launch_bounds__(256) void k_comb(const float* __restrict__ lse_ws,
                                              const u16* __restrict__ att_ws,
                                              float* __restrict__ out){
  size_t idx = (size_t)blockIdx.x * 256 + threadIdx.x;   // over B*S*D
  size_t pd = idx >> 6;
  int d = (int)(idx & 63);
  float4 lv = *(const float4*)(lse_ws + pd * 4);
  float m = fmaxf(fmaxf(lv.x, lv.y), fmaxf(lv.z, lv.w));
  float e0 = __expf(lv.x - m), e1 = __expf(lv.y - m);
  float e2 = __expf(lv.z - m), e3 = __expf(lv.w - m);
  float inv = 1.0f / (e0 + e1 + e2 + e3);
  const u16* a = att_ws + pd * 256 + d;
  float o = (bf2f(a[0])   * e0 + bf2f(a[64])  * e1 +
             bf2f(a[128]) * e2 + bf2f(a[192]) * e3) * inv;
  out[idx] = o;
}

// ---------------------------------------------------------------------------
extern "C" void kernel_launch(void* const* d_in, const int* in_sizes, int n_in,
                              void* d_out, int out_size, void* d_ws, size_t ws_size,
                              hipStream_t stream){
  const float* q = (const float*)d_in[0];   // (32,2048,64) f32
  const float* v = (const float*)d_in[1];   // (32,2048,64) f32
  const float* R = (const float*)d_in[2];   // (32,64,4,16) f32

  char* w = (char*)d_ws;
  int*   h    = (int*)  (w + 0);                 // (32,4,2048) i32   1 MB
  int*   sidx = (int*)  (w + (1u << 20));        // (32,4,2048) i32   1 MB
  int*   chkA = (int*)  (w + (2u << 20));        // (32,4,2048) i32   1 MB
  float* lse  = (float*)(w + (3u << 20));        // (32,2048,4) f32   1 MB
  u16*   att  = (u16*)  (w + (4u << 20));        // (32,2048,4,64) bf16  32 MB
  float* out  = (float*)d_out;

  k_hash<<<256,  256, 0, stream>>>(q, R, h);
  k_sort<<<128,  256, 0, stream>>>(h, sidx, chkA);
  k_attn<<<4096, 256, 0, stream>>>(q, v, sidx, chkA, lse, att);
  k_comb<<<16384,256, 0, stream>>>(lse, att, out);
}